// Round 1
// baseline (3976.523 us; speedup 1.0000x reference)
//
#include <hip/hip_runtime.h>
#include <hip/hip_bf16.h>
#include <math.h>

// Problem constants
#define BB 4
#define TT 2048
#define CC 1024
#define HH 16
#define DD 64
#define C3 3072

// ---------------------------------------------------------------------------
// Simple fp32 tiled GEMM: C[M,N] = A[M,K] @ B[K,N], all row-major.
// 64x64 block tile, K-step 16, 256 threads, 4x4 acc per thread.
// ---------------------------------------------------------------------------
__global__ __launch_bounds__(256) void gemm64(const float* __restrict__ A,
                                              const float* __restrict__ B,
                                              float* __restrict__ C,
                                              int M, int N, int K) {
    __shared__ float As[16][68];   // As[k][m], padded so float4 row reads stay 16B-aligned
    __shared__ float Bs[16][64];   // Bs[k][n]

    const int tid = threadIdx.x;
    const int tx = tid & 15;       // n group (4 cols each)
    const int ty = tid >> 4;       // m group (4 rows each)
    const int m0 = blockIdx.y * 64;
    const int n0 = blockIdx.x * 64;

    float acc[4][4];
#pragma unroll
    for (int i = 0; i < 4; ++i)
#pragma unroll
        for (int j = 0; j < 4; ++j) acc[i][j] = 0.f;

    // A staging: thread loads 4 scalars: rows ar..ar+3, col ac
    const int ar = (tid >> 4) * 4;
    const int ac = tid & 15;
    // B staging: thread loads one float4: row bc, cols bn..bn+3
    const int bc = tid >> 4;
    const int bn = (tid & 15) * 4;

    for (int k0 = 0; k0 < K; k0 += 16) {
        __syncthreads();  // protect previous tile's reads before overwrite
#pragma unroll
        for (int i = 0; i < 4; ++i) {
            As[ac][ar + i] = A[(size_t)(m0 + ar + i) * K + k0 + ac];
        }
        float4 bv = *reinterpret_cast<const float4*>(&B[(size_t)(k0 + bc) * N + n0 + bn]);
        *reinterpret_cast<float4*>(&Bs[bc][bn]) = bv;
        __syncthreads();
#pragma unroll
        for (int k = 0; k < 16; ++k) {
            float4 a = *reinterpret_cast<const float4*>(&As[k][ty * 4]);
            float4 b = *reinterpret_cast<const float4*>(&Bs[k][tx * 4]);
            float av[4] = {a.x, a.y, a.z, a.w};
            float bw[4] = {b.x, b.y, b.z, b.w};
#pragma unroll
            for (int i = 0; i < 4; ++i)
#pragma unroll
                for (int j = 0; j < 4; ++j) acc[i][j] += av[i] * bw[j];
        }
    }

#pragma unroll
    for (int i = 0; i < 4; ++i) {
        float4 v = make_float4(acc[i][0], acc[i][1], acc[i][2], acc[i][3]);
        *reinterpret_cast<float4*>(&C[(size_t)(m0 + ty * 4 + i) * N + n0 + tx * 4]) = v;
    }
}

// ---------------------------------------------------------------------------
// Flash-style causal attention, fp32.
// Block = 256 threads = 4 waves; wave w handles q row q0+w of head (b,h).
// K/V tiles (64 keys x 64 dims) staged in LDS cooperatively.
// Per-lane-key scores; online softmax with wave shuffles; PV via LDS bounce.
// qkv layout: [B,T,3C] fp32 with q at +0, k at +C, v at +2C; head offset h*D.
// ---------------------------------------------------------------------------
__global__ __launch_bounds__(256) void attn_fwd(const float* __restrict__ qkv,
                                                const int* __restrict__ amask,
                                                float* __restrict__ y) {
    __shared__ float Kt[64][65];   // +1 pad: Kt[lane][d] and Vt[j][lane] conflict-free
    __shared__ float Vt[64][65];
    __shared__ float qrow[4][64];
    __shared__ float pbuf[4][64];

    const int tid  = threadIdx.x;
    const int lane = tid & 63;
    const int w    = tid >> 6;
    const int b    = blockIdx.z;
    const int h    = blockIdx.y;
    const int q0   = blockIdx.x * 4;
    const int q    = q0 + w;

    // Load this wave's q row (lane = d)
    qrow[w][lane] = qkv[(size_t)(b * TT + q) * C3 + h * DD + lane];

    float m = -INFINITY, l = 0.f, acc = 0.f;

    const int ntiles = (q0 + 3) / 64 + 1;

    // Staging: each thread moves 16 floats of K and 16 of V (4x float4)
    const int sj = tid >> 2;          // key row 0..63
    const int sd = (tid & 3) * 16;    // dim start

    for (int t = 0; t < ntiles; ++t) {
        __syncthreads();
        {
            const size_t kbase = (size_t)(b * TT + t * 64 + sj) * C3 + h * DD + sd;
#pragma unroll
            for (int u = 0; u < 4; ++u) {
                float4 kv = *reinterpret_cast<const float4*>(&qkv[kbase + CC + u * 4]);
                float4 vv = *reinterpret_cast<const float4*>(&qkv[kbase + 2 * CC + u * 4]);
                Kt[sj][sd + u * 4 + 0] = kv.x;
                Kt[sj][sd + u * 4 + 1] = kv.y;
                Kt[sj][sd + u * 4 + 2] = kv.z;
                Kt[sj][sd + u * 4 + 3] = kv.w;
                Vt[sj][sd + u * 4 + 0] = vv.x;
                Vt[sj][sd + u * 4 + 1] = vv.y;
                Vt[sj][sd + u * 4 + 2] = vv.z;
                Vt[sj][sd + u * 4 + 3] = vv.w;
            }
        }
        __syncthreads();

        // Score for key j = lane
        float s = 0.f;
#pragma unroll
        for (int d = 0; d < 64; ++d) s += Kt[lane][d] * qrow[w][d];

        const int kidx = t * 64 + lane;
        const bool valid = (kidx <= q) && (amask[b * TT + kidx] != 0);
        s = valid ? s * 0.125f : -INFINITY;

        // wave max of tile scores
        float tm = s;
#pragma unroll
        for (int off = 32; off >= 1; off >>= 1) tm = fmaxf(tm, __shfl_xor(tm, off));
        const float mnew = fmaxf(m, tm);
        const float p = expf(s - mnew);
        const float alpha = expf(m - mnew);

        // wave sum of p
        float ps = p;
#pragma unroll
        for (int off = 32; off >= 1; off >>= 1) ps += __shfl_xor(ps, off);
        l = l * alpha + ps;

        pbuf[w][lane] = p;
        __syncthreads();

        // PV: lane owns output dim d = lane
        float sum = 0.f;
#pragma unroll
        for (int j = 0; j < 64; ++j) sum += pbuf[w][j] * Vt[j][lane];
        acc = acc * alpha + sum;

        m = mnew;
    }

    y[(size_t)(b * TT + q) * CC + h * DD + lane] = acc / l;
}

// ---------------------------------------------------------------------------
extern "C" void kernel_launch(void* const* d_in, const int* in_sizes, int n_in,
                              void* d_out, int out_size, void* d_ws, size_t ws_size,
                              hipStream_t stream) {
    const float* x      = (const float*)d_in[0];
    const int*   amask  = (const int*)d_in[1];
    const float* W_attn = (const float*)d_in[2];
    const float* W_proj = (const float*)d_in[3];
    float* out = (float*)d_out;

    // Workspace: qkv fp32 [B,T,3C] then y fp32 [B,T,C]
    float* qkv = (float*)d_ws;
    float* y   = qkv + (size_t)BB * TT * C3;

    const int M = BB * TT;  // 8192

    // 1) qkv = x @ W_attn   [8192,1024]x[1024,3072]
    {
        dim3 grid(C3 / 64, M / 64);
        gemm64<<<grid, 256, 0, stream>>>(x, W_attn, qkv, M, C3, CC);
    }
    // 2) attention -> y [B,T,C]
    {
        dim3 grid(TT / 4, HH, BB);
        attn_fwd<<<grid, 256, 0, stream>>>(qkv, amask, y);
    }
    // 3) out = y @ W_proj   [8192,1024]x[1024,1024]
    {
        dim3 grid(CC / 64, M / 64);
        gemm64<<<grid, 256, 0, stream>>>(y, W_proj, out, M, CC, CC);
    }
}

// Round 2
// 362.422 us; speedup vs baseline: 10.9721x; 10.9721x over previous
//
#include <hip/hip_runtime.h>
#include <hip/hip_bf16.h>
#include <math.h>

#define TT 2048
#define CC 1024
#define HH 16
#define C3 3072
#define MM 8192   // B*T

typedef __attribute__((ext_vector_type(8))) short short8;
typedef __attribute__((ext_vector_type(4))) float f32x4;

__device__ __forceinline__ short bf16b(float x) {
  __hip_bfloat16 h = __float2bfloat16(x);
  return *reinterpret_cast<short*>(&h);
}

__device__ __forceinline__ void gload16(const void* g, void* l) {
  __builtin_amdgcn_global_load_lds(
      (const __attribute__((address_space(1))) unsigned int*)g,
      (__attribute__((address_space(3))) unsigned int*)l, 16, 0, 0);
}

// ---------------------------------------------------------------------------
// fp32 -> bf16 bits, 8 elems/thread
// ---------------------------------------------------------------------------
__global__ __launch_bounds__(256) void cvt_x(const float* __restrict__ in,
                                             short* __restrict__ out, int n) {
  int i = (blockIdx.x * 256 + threadIdx.x) * 8;
  if (i >= n) return;
  float4 a = *reinterpret_cast<const float4*>(in + i);
  float4 b = *reinterpret_cast<const float4*>(in + i + 4);
  short8 r;
  r[0] = bf16b(a.x); r[1] = bf16b(a.y); r[2] = bf16b(a.z); r[3] = bf16b(a.w);
  r[4] = bf16b(b.x); r[5] = bf16b(b.y); r[6] = bf16b(b.z); r[7] = bf16b(b.w);
  *reinterpret_cast<short8*>(out + i) = r;
}

// ---------------------------------------------------------------------------
// transpose + convert: in [R][Cc] fp32 -> out [Cc][R] bf16
// ---------------------------------------------------------------------------
__global__ __launch_bounds__(256) void cvt_t(const float* __restrict__ in,
                                             short* __restrict__ out, int R, int Cc) {
  __shared__ float t[32][33];
  int c0 = blockIdx.x * 32, r0 = blockIdx.y * 32;
  int tx = threadIdx.x & 31, ty = threadIdx.x >> 5;
#pragma unroll
  for (int i = 0; i < 4; ++i)
    t[ty + i * 8][tx] = in[(size_t)(r0 + ty + i * 8) * Cc + c0 + tx];
  __syncthreads();
#pragma unroll
  for (int i = 0; i < 4; ++i)
    out[(size_t)(c0 + ty + i * 8) * R + r0 + tx] = bf16b(t[tx][ty + i * 8]);
}

// ---------------------------------------------------------------------------
// bf16 MFMA GEMM: C[M,N] = A[M,K] * Bt[N,K]^T.  128x128 tile, BK=32,
// 256 threads = 4 waves (2x2), 4x4 16x16 frags/wave, global_load_lds staging.
// ---------------------------------------------------------------------------
template <int OUT_BF16>
__global__ __launch_bounds__(256) void gemm_bt(const short* __restrict__ A,
                                               const short* __restrict__ Bt,
                                               void* __restrict__ Cout,
                                               int M, int N, int K) {
  __shared__ __align__(16) short As[128 * 32];
  __shared__ __align__(16) short Bs[128 * 32];
  const int tid = threadIdx.x, lane = tid & 63, w = tid >> 6;
  const int g = lane >> 4, cw = lane & 15;
  const int m0 = blockIdx.y * 128, n0 = blockIdx.x * 128;
  const int wr = (w >> 1) * 64, wc = (w & 1) * 64;

  f32x4 acc[4][4];
#pragma unroll
  for (int i = 0; i < 4; ++i)
#pragma unroll
    for (int j = 0; j < 4; ++j) acc[i][j] = (f32x4){0.f, 0.f, 0.f, 0.f};

  const int srow = w * 16 + (lane >> 2);  // + u*64
  const int scol = (lane & 3) * 8;        // k elements

  for (int k0 = 0; k0 < K; k0 += 32) {
    __syncthreads();
#pragma unroll
    for (int u = 0; u < 2; ++u) {
      gload16(A + (size_t)(m0 + srow + u * 64) * K + k0 + scol,
              (char*)As + u * 4096 + w * 1024);
      gload16(Bt + (size_t)(n0 + srow + u * 64) * K + k0 + scol,
              (char*)Bs + u * 4096 + w * 1024);
    }
    __syncthreads();
    short8 af[4], bf[4];
#pragma unroll
    for (int mt = 0; mt < 4; ++mt)
      af[mt] = *reinterpret_cast<const short8*>(&As[(wr + mt * 16 + cw) * 32 + g * 8]);
#pragma unroll
    for (int nt = 0; nt < 4; ++nt)
      bf[nt] = *reinterpret_cast<const short8*>(&Bs[(wc + nt * 16 + cw) * 32 + g * 8]);
#pragma unroll
    for (int mt = 0; mt < 4; ++mt)
#pragma unroll
      for (int nt = 0; nt < 4; ++nt)
        acc[mt][nt] = __builtin_amdgcn_mfma_f32_16x16x32_bf16(af[mt], bf[nt], acc[mt][nt], 0, 0, 0);
  }

#pragma unroll
  for (int mt = 0; mt < 4; ++mt)
#pragma unroll
    for (int nt = 0; nt < 4; ++nt)
#pragma unroll
      for (int j = 0; j < 4; ++j) {
        int row = m0 + wr + mt * 16 + g * 4 + j;
        int col = n0 + wc + nt * 16 + cw;
        if (OUT_BF16)
          ((short*)Cout)[(size_t)row * N + col] = bf16b(acc[mt][nt][j]);
        else
          ((float*)Cout)[(size_t)row * N + col] = acc[mt][nt][j];
      }
}

// ---------------------------------------------------------------------------
// Flash attention, bf16 MFMA.  Block = 4 waves; wave w owns 32 q rows.
// Q-tile 128, K/V-tile 64.  Kt LDS XOR-swizzled; Vt stored transposed [d][key]
// (swizzled); P bounced via swizzled LDS for PV A-frags.
// qkv bf16 [B,T,3C]: q at +0, k at +C, v at +2C, head offset h*64.
// ---------------------------------------------------------------------------
__global__ __launch_bounds__(256) void attn_mfma(const short* __restrict__ qkv,
                                                 const int* __restrict__ amask,
                                                 short* __restrict__ y) {
  __shared__ __align__(16) short Kt[64 * 64];
  __shared__ __align__(16) short Vt[64 * 64];   // [d][key]
  __shared__ __align__(16) short Pb[4][32 * 64];
  __shared__ int am[64];

  const int tid = threadIdx.x, lane = tid & 63, w = tid >> 6;
  const int g = lane >> 4, cw = lane & 15;
  const int bh = blockIdx.y, b = bh >> 4, h = bh & 15;
  const int q0 = blockIdx.x * 128;
  const int qw = q0 + w * 32;

  // Q fragments (registers, once)
  short8 qf[2][2];
#pragma unroll
  for (int mt = 0; mt < 2; ++mt)
#pragma unroll
    for (int ks = 0; ks < 2; ++ks)
      qf[mt][ks] = *reinterpret_cast<const short8*>(
          &qkv[(size_t)(b * TT + qw + mt * 16 + cw) * C3 + h * 64 + ks * 32 + g * 8]);

  f32x4 o[2][4];
#pragma unroll
  for (int mt = 0; mt < 2; ++mt)
#pragma unroll
    for (int nt = 0; nt < 4; ++nt) o[mt][nt] = (f32x4){0.f, 0.f, 0.f, 0.f};
  float mx[2][4], lsum[2][4];
#pragma unroll
  for (int mt = 0; mt < 2; ++mt)
#pragma unroll
    for (int j = 0; j < 4; ++j) { mx[mt][j] = -INFINITY; lsum[mt][j] = 0.f; }

  const int ntiles = q0 / 64 + 2;
  const int skey = tid >> 2;
  const int sd = (tid & 3) * 16;

  for (int t = 0; t < ntiles; ++t) {
    __syncthreads();
    // ---- stage K (swizzled rows) and V (transposed, swizzled) ----
    const size_t kvbase = (size_t)(b * TT + t * 64 + skey) * C3 + h * 64 + sd;
#pragma unroll
    for (int u = 0; u < 2; ++u) {
      short8 kv = *reinterpret_cast<const short8*>(&qkv[kvbase + CC + u * 8]);
      short8 vv = *reinterpret_cast<const short8*>(&qkv[kvbase + 2 * CC + u * 8]);
      int cb = (sd + u * 8) * 2;
      *reinterpret_cast<short8*>((char*)Kt + skey * 128 + (cb ^ ((skey & 7) << 4))) = kv;
#pragma unroll
      for (int i = 0; i < 8; ++i) {
        int d = sd + u * 8 + i;
        *(short*)((char*)Vt + d * 128 + ((skey * 2) ^ ((d & 7) << 4))) = vv[i];
      }
    }
    if (tid < 64) am[tid] = amask[b * TT + t * 64 + tid];
    __syncthreads();

    // ---- S = Q K^T ----
    f32x4 s[2][4];
#pragma unroll
    for (int nt = 0; nt < 4; ++nt) {
      const int krow = nt * 16 + cw;
#pragma unroll
      for (int ks = 0; ks < 2; ++ks) {
        short8 kb = *reinterpret_cast<const short8*>(
            (char*)Kt + krow * 128 + (((ks * 32 + g * 8) * 2) ^ ((krow & 7) << 4)));
        if (ks == 0) {
          f32x4 z = (f32x4){0.f, 0.f, 0.f, 0.f};
          s[0][nt] = __builtin_amdgcn_mfma_f32_16x16x32_bf16(qf[0][0], kb, z, 0, 0, 0);
          s[1][nt] = __builtin_amdgcn_mfma_f32_16x16x32_bf16(qf[1][0], kb, z, 0, 0, 0);
        } else {
          s[0][nt] = __builtin_amdgcn_mfma_f32_16x16x32_bf16(qf[0][1], kb, s[0][nt], 0, 0, 0);
          s[1][nt] = __builtin_amdgcn_mfma_f32_16x16x32_bf16(qf[1][1], kb, s[1][nt], 0, 0, 0);
        }
      }
    }

    // ---- mask + scale ----
#pragma unroll
    for (int nt = 0; nt < 4; ++nt) {
      const int key = t * 64 + nt * 16 + cw;
      const bool amok = am[nt * 16 + cw] != 0;
#pragma unroll
      for (int mt = 0; mt < 2; ++mt)
#pragma unroll
        for (int j = 0; j < 4; ++j) {
          const int qrow = qw + mt * 16 + g * 4 + j;
          const bool valid = (key <= qrow) && amok;
          s[mt][nt][j] = valid ? s[mt][nt][j] * 0.125f : -INFINITY;
        }
    }

    // ---- online softmax (wave-parallel, 16-lane-group reduces) ----
#pragma unroll
    for (int mt = 0; mt < 2; ++mt) {
      float al[4];
#pragma unroll
      for (int j = 0; j < 4; ++j) {
        float v = fmaxf(fmaxf(s[mt][0][j], s[mt][1][j]), fmaxf(s[mt][2][j], s[mt][3][j]));
#pragma unroll
        for (int off = 8; off >= 1; off >>= 1) v = fmaxf(v, __shfl_xor(v, off));
        float mn = fmaxf(mx[mt][j], v);
        al[j] = __expf(mx[mt][j] - mn);
        mx[mt][j] = mn;
      }
      float rs[4] = {0.f, 0.f, 0.f, 0.f};
#pragma unroll
      for (int nt = 0; nt < 4; ++nt)
#pragma unroll
        for (int j = 0; j < 4; ++j) {
          float p = __expf(s[mt][nt][j] - mx[mt][j]);
          s[mt][nt][j] = p;
          rs[j] += p;
        }
#pragma unroll
      for (int j = 0; j < 4; ++j) {
#pragma unroll
        for (int off = 8; off >= 1; off >>= 1) rs[j] += __shfl_xor(rs[j], off);
        lsum[mt][j] = lsum[mt][j] * al[j] + rs[j];
      }
#pragma unroll
      for (int ntd = 0; ntd < 4; ++ntd)
#pragma unroll
        for (int j = 0; j < 4; ++j) o[mt][ntd][j] *= al[j];
      // P -> LDS (bf16, swizzled)
#pragma unroll
      for (int nt = 0; nt < 4; ++nt)
#pragma unroll
        for (int j = 0; j < 4; ++j) {
          const int row = mt * 16 + g * 4 + j;
          *(short*)((char*)&Pb[w][0] + row * 128 + (((nt * 16 + cw) * 2) ^ ((row & 7) << 4))) =
              bf16b(s[mt][nt][j]);
        }
    }

    // ---- O += P V ----
#pragma unroll
    for (int ks2 = 0; ks2 < 2; ++ks2) {
      short8 pafr[2];
#pragma unroll
      for (int mt = 0; mt < 2; ++mt) {
        const int prow = mt * 16 + cw;
        pafr[mt] = *reinterpret_cast<const short8*>(
            (char*)&Pb[w][0] + prow * 128 + (((ks2 * 32 + g * 8) * 2) ^ ((prow & 7) << 4)));
      }
#pragma unroll
      for (int ntd = 0; ntd < 4; ++ntd) {
        const int drow = ntd * 16 + cw;
        short8 vb = *reinterpret_cast<const short8*>(
            (char*)Vt + drow * 128 + (((ks2 * 32 + g * 8) * 2) ^ ((drow & 7) << 4)));
#pragma unroll
        for (int mt = 0; mt < 2; ++mt)
          o[mt][ntd] = __builtin_amdgcn_mfma_f32_16x16x32_bf16(pafr[mt], vb, o[mt][ntd], 0, 0, 0);
      }
    }
  }

  // ---- epilogue: y = O / l ----
#pragma unroll
  for (int mt = 0; mt < 2; ++mt)
#pragma unroll
    for (int ntd = 0; ntd < 4; ++ntd)
#pragma unroll
      for (int j = 0; j < 4; ++j) {
        const int q = qw + mt * 16 + g * 4 + j;
        const int d = ntd * 16 + cw;
        y[(size_t)(b * TT + q) * CC + h * 64 + d] = bf16b(o[mt][ntd][j] / lsum[mt][j]);
      }
}

// ---------------------------------------------------------------------------
extern "C" void kernel_launch(void* const* d_in, const int* in_sizes, int n_in,
                              void* d_out, int out_size, void* d_ws, size_t ws_size,
                              hipStream_t stream) {
  const float* x      = (const float*)d_in[0];
  const int*   amask  = (const int*)d_in[1];
  const float* W_attn = (const float*)d_in[2];
  const float* W_proj = (const float*)d_in[3];
  float* out = (float*)d_out;

  char* ws = (char*)d_ws;
  short* xb  = (short*)(ws);                    // [8192][1024] bf16   16.8 MB
  short* Wta = (short*)(ws + 16777216);         // [3072][1024] bf16    6.3 MB
  short* Wtp = (short*)(ws + 23068672);         // [1024][1024] bf16    2.1 MB
  short* qkv = (short*)(ws + 25165824);         // [8192][3072] bf16   50.3 MB
  short* y   = (short*)(ws + 75497472);         // [8192][1024] bf16   16.8 MB

  cvt_x<<<MM * CC / (256 * 8), 256, 0, stream>>>(x, xb, MM * CC);
  {
    dim3 g(C3 / 32, CC / 32);
    cvt_t<<<g, 256, 0, stream>>>(W_attn, Wta, CC, C3);
  }
  {
    dim3 g(CC / 32, CC / 32);
    cvt_t<<<g, 256, 0, stream>>>(W_proj, Wtp, CC, CC);
  }
  {
    dim3 g(C3 / 128, MM / 128);
    gemm_bt<1><<<g, 256, 0, stream>>>(xb, Wta, qkv, MM, C3, CC);
  }
  {
    dim3 g(TT / 128, 64);
    attn_mfma<<<g, 256, 0, stream>>>(qkv, amask, y);
  }
  {
    dim3 g(CC / 128, MM / 128);
    gemm_bt<0><<<g, 256, 0, stream>>>(y, Wtp, out, MM, CC, CC);
  }
}

// Round 3
// 222.396 us; speedup vs baseline: 17.8804x; 1.6296x over previous
//
#include <hip/hip_runtime.h>
#include <hip/hip_bf16.h>
#include <math.h>

#define TT 2048
#define CC 1024
#define C3 3072
#define MM 8192   // B*T

typedef __attribute__((ext_vector_type(8))) short short8;
typedef __attribute__((ext_vector_type(4))) float f32x4;

__device__ __forceinline__ short bf16b(float x) {
  __hip_bfloat16 h = __float2bfloat16(x);
  return *reinterpret_cast<short*>(&h);
}

__device__ __forceinline__ unsigned cvtpk(float lo, float hi) {
  unsigned r;
  asm("v_cvt_pk_bf16_f32 %0, %1, %2" : "=v"(r) : "v"(lo), "v"(hi));
  return r;
}

__device__ __forceinline__ void gload16(const void* g, void* l) {
  __builtin_amdgcn_global_load_lds(
      (const __attribute__((address_space(1))) unsigned int*)g,
      (__attribute__((address_space(3))) unsigned int*)l, 16, 0, 0);
}

// ---------------------------------------------------------------------------
// fp32 -> bf16 bits, 8 elems/thread
// ---------------------------------------------------------------------------
__global__ __launch_bounds__(256) void cvt_x(const float* __restrict__ in,
                                             short* __restrict__ out, int n) {
  int i = (blockIdx.x * 256 + threadIdx.x) * 8;
  if (i >= n) return;
  float4 a = *reinterpret_cast<const float4*>(in + i);
  float4 b = *reinterpret_cast<const float4*>(in + i + 4);
  short8 r;
  r[0] = bf16b(a.x); r[1] = bf16b(a.y); r[2] = bf16b(a.z); r[3] = bf16b(a.w);
  r[4] = bf16b(b.x); r[5] = bf16b(b.y); r[6] = bf16b(b.z); r[7] = bf16b(b.w);
  *reinterpret_cast<short8*>(out + i) = r;
}

// ---------------------------------------------------------------------------
// transpose + convert: in [R][Cc] fp32 -> out [Cc][R] bf16
// ---------------------------------------------------------------------------
__global__ __launch_bounds__(256) void cvt_t(const float* __restrict__ in,
                                             short* __restrict__ out, int R, int Cc) {
  __shared__ float t[32][33];
  int c0 = blockIdx.x * 32, r0 = blockIdx.y * 32;
  int tx = threadIdx.x & 31, ty = threadIdx.x >> 5;
#pragma unroll
  for (int i = 0; i < 4; ++i)
    t[ty + i * 8][tx] = in[(size_t)(r0 + ty + i * 8) * Cc + c0 + tx];
  __syncthreads();
#pragma unroll
  for (int i = 0; i < 4; ++i)
    out[(size_t)(c0 + ty + i * 8) * R + r0 + tx] = bf16b(t[tx][ty + i * 8]);
}

// ---------------------------------------------------------------------------
// V transpose + key-permute: qkv V-part [B,T,(2C..3C)] -> vT[bh][d][t'] where
// within each 32-key window, position p holds key tl(p):
//   tl = (p&32) | ((p>>2)&1)<<4 | ((p>>3)&3)<<2 | (p&3)
// so that PV A-fragment key slots (lane g holds slots g*8..g*8+7) line up
// with the keys the lane naturally holds after swapped QK^T.
// ---------------------------------------------------------------------------
__global__ __launch_bounds__(256) void vtrans(const short* __restrict__ qkv,
                                              short* __restrict__ vT) {
  __shared__ short tile[64][72];
  const int bh = blockIdx.y, b = bh >> 4, h = bh & 15;
  const int t0 = blockIdx.x * 64;
  const int tr = threadIdx.x >> 2, dc = (threadIdx.x & 3) * 16;
  const short* src = qkv + (size_t)(b * TT + t0 + tr) * C3 + 2 * CC + h * 64 + dc;
  *reinterpret_cast<short8*>(&tile[tr][dc]) = *reinterpret_cast<const short8*>(src);
  *reinterpret_cast<short8*>(&tile[tr][dc + 8]) = *reinterpret_cast<const short8*>(src + 8);
  __syncthreads();
  const int d = threadIdx.x >> 2, p0 = (threadIdx.x & 3) * 16;
  short8 o1, o2;
#pragma unroll
  for (int i = 0; i < 8; ++i) {
    int p = p0 + i;
    int tl = (p & 32) | (((p >> 2) & 1) << 4) | (((p >> 3) & 3) << 2) | (p & 3);
    o1[i] = tile[tl][d];
    p = p0 + 8 + i;
    tl = (p & 32) | (((p >> 2) & 1) << 4) | (((p >> 3) & 3) << 2) | (p & 3);
    o2[i] = tile[tl][d];
  }
  short* dst = vT + (size_t)(bh * 64 + d) * TT + t0 + p0;
  *reinterpret_cast<short8*>(dst) = o1;
  *reinterpret_cast<short8*>(dst + 8) = o2;
}

// ---------------------------------------------------------------------------
// bf16 MFMA GEMM: C[M,N] = A[M,K] * Bt[N,K]^T.  128x128 tile, BK=32,
// 256 threads = 4 waves (2x2), 4x4 16x16 frags/wave, global_load_lds staging.
// ---------------------------------------------------------------------------
template <int OUT_BF16>
__global__ __launch_bounds__(256) void gemm_bt(const short* __restrict__ A,
                                               const short* __restrict__ Bt,
                                               void* __restrict__ Cout,
                                               int M, int N, int K) {
  __shared__ __align__(16) short As[128 * 32];
  __shared__ __align__(16) short Bs[128 * 32];
  const int tid = threadIdx.x, lane = tid & 63, w = tid >> 6;
  const int g = lane >> 4, cw = lane & 15;
  const int m0 = blockIdx.y * 128, n0 = blockIdx.x * 128;
  const int wr = (w >> 1) * 64, wc = (w & 1) * 64;

  f32x4 acc[4][4];
#pragma unroll
  for (int i = 0; i < 4; ++i)
#pragma unroll
    for (int j = 0; j < 4; ++j) acc[i][j] = (f32x4){0.f, 0.f, 0.f, 0.f};

  const int srow = w * 16 + (lane >> 2);  // + u*64
  const int scol = (lane & 3) * 8;        // k elements

  for (int k0 = 0; k0 < K; k0 += 32) {
    __syncthreads();
#pragma unroll
    for (int u = 0; u < 2; ++u) {
      gload16(A + (size_t)(m0 + srow + u * 64) * K + k0 + scol,
              (char*)As + u * 4096 + w * 1024);
      gload16(Bt + (size_t)(n0 + srow + u * 64) * K + k0 + scol,
              (char*)Bs + u * 4096 + w * 1024);
    }
    __syncthreads();
    short8 af[4], bf[4];
#pragma unroll
    for (int mt = 0; mt < 4; ++mt)
      af[mt] = *reinterpret_cast<const short8*>(&As[(wr + mt * 16 + cw) * 32 + g * 8]);
#pragma unroll
    for (int nt = 0; nt < 4; ++nt)
      bf[nt] = *reinterpret_cast<const short8*>(&Bs[(wc + nt * 16 + cw) * 32 + g * 8]);
#pragma unroll
    for (int mt = 0; mt < 4; ++mt)
#pragma unroll
      for (int nt = 0; nt < 4; ++nt)
        acc[mt][nt] = __builtin_amdgcn_mfma_f32_16x16x32_bf16(af[mt], bf[nt], acc[mt][nt], 0, 0, 0);
  }

#pragma unroll
  for (int mt = 0; mt < 4; ++mt)
#pragma unroll
    for (int nt = 0; nt < 4; ++nt)
#pragma unroll
      for (int j = 0; j < 4; ++j) {
        int row = m0 + wr + mt * 16 + g * 4 + j;
        int col = n0 + wc + nt * 16 + cw;
        if (OUT_BF16)
          ((short*)Cout)[(size_t)row * N + col] = bf16b(acc[mt][nt][j]);
        else
          ((float*)Cout)[(size_t)row * N + col] = acc[mt][nt][j];
      }
}

// ---------------------------------------------------------------------------
// Flash attention, swapped-operand MFMA.
// Block = 4 waves; wave w owns 32 q rows; q-tile 128; KV-tile 64.
// Causal pairing: blockIdx.x=i handles q-tiles {i, 15-i} (34 KV-tiles total).
// QK^T computed as mfma(K, Q) -> lane holds S^T with q = lane&15, so softmax
// is 15 local fmax + 2 shfl_xor.  P packs straight into PV A-frags (cvt_pk,
// zero shuffles) because vT is stored key-permuted.  K and permuted-V^T are
// staged via global_load_lds with XOR-swizzle pre-applied to the SOURCE addr.
// ---------------------------------------------------------------------------
__global__ __launch_bounds__(256) void attn_mfma(const short* __restrict__ qkv,
                                                 const short* __restrict__ vT,
                                                 const int* __restrict__ amask,
                                                 short* __restrict__ y) {
  __shared__ __align__(16) char Ks[8192];   // [key][128B], swizzled
  __shared__ __align__(16) char Vs[8192];   // [d][128B perm-keys], swizzled
  const int tid = threadIdx.x, lane = tid & 63, w = tid >> 6;
  const int g = lane >> 4, cw = lane & 15;
  const int bh = blockIdx.y, b = bh >> 4, h = bh & 15;
  const int xorm = (cw & 7) << 4;
  const int srow = w * 8 + (lane >> 3);                    // staging row (+u*32)
  const int scb = (((lane & 7) ^ (lane >> 3)) << 4);       // pre-swizzled src col byte

#pragma unroll 1
  for (int part = 0; part < 2; ++part) {
    const int qt = part ? 15 - (int)blockIdx.x : (int)blockIdx.x;
    const int q0 = qt * 128;
    const int qw = q0 + w * 32;

    // Q fragments (B-operand: lane holds Q[q = qw+mt*16+cw][d contiguous])
    short8 qf[2][2];
#pragma unroll
    for (int mt = 0; mt < 2; ++mt)
#pragma unroll
      for (int ks = 0; ks < 2; ++ks)
        qf[mt][ks] = *reinterpret_cast<const short8*>(
            &qkv[(size_t)(b * TT + qw + mt * 16 + cw) * C3 + h * 64 + ks * 32 + g * 8]);

    f32x4 o[2][4];
#pragma unroll
    for (int mt = 0; mt < 2; ++mt)
#pragma unroll
      for (int nd = 0; nd < 4; ++nd) o[mt][nd] = (f32x4){0.f, 0.f, 0.f, 0.f};
    float mx[2] = {-1e30f, -1e30f}, ls[2] = {0.f, 0.f};

    const int ntiles = 2 * qt + 2;
    for (int t = 0; t < ntiles; ++t) {
      __syncthreads();
#pragma unroll
      for (int u = 0; u < 2; ++u) {
        const int r = u * 32 + srow;
        gload16((const char*)qkv +
                    ((size_t)(b * TT + t * 64 + r) * C3 + CC + h * 64) * 2 + scb,
                Ks + u * 4096 + w * 1024 + lane * 16);
        gload16((const char*)vT + ((size_t)(bh * 64 + r) * TT + t * 64) * 2 + scb,
                Vs + u * 4096 + w * 1024 + lane * 16);
      }
      const unsigned long long kbits = __ballot(amask[b * TT + t * 64 + lane] != 0);
      __syncthreads();

      // ---- S^T = K Q^T : lane holds q = cw, keys nt*16 + g*4 + j ----
      f32x4 s[2][4];
#pragma unroll
      for (int nt = 0; nt < 4; ++nt) {
        const int r = nt * 16 + cw;
#pragma unroll
        for (int ks = 0; ks < 2; ++ks) {
          short8 kf = *reinterpret_cast<const short8*>(
              Ks + r * 128 + ((ks * 64 + g * 16) ^ xorm));
          if (ks == 0) {
            f32x4 z = (f32x4){0.f, 0.f, 0.f, 0.f};
            s[0][nt] = __builtin_amdgcn_mfma_f32_16x16x32_bf16(kf, qf[0][0], z, 0, 0, 0);
            s[1][nt] = __builtin_amdgcn_mfma_f32_16x16x32_bf16(kf, qf[1][0], z, 0, 0, 0);
          } else {
            s[0][nt] = __builtin_amdgcn_mfma_f32_16x16x32_bf16(kf, qf[0][1], s[0][nt], 0, 0, 0);
            s[1][nt] = __builtin_amdgcn_mfma_f32_16x16x32_bf16(kf, qf[1][1], s[1][nt], 0, 0, 0);
          }
        }
      }

      // ---- mask + scale ----
#pragma unroll
      for (int nt = 0; nt < 4; ++nt)
#pragma unroll
        for (int j = 0; j < 4; ++j) {
          const int kh = nt * 16 + g * 4 + j;
          const int key = t * 64 + kh;
          const bool mok = (kbits >> kh) & 1;
#pragma unroll
          for (int mt = 0; mt < 2; ++mt) {
            const int q = qw + mt * 16 + cw;
            s[mt][nt][j] = (mok && key <= q) ? s[mt][nt][j] * 0.125f : -1e30f;
          }
        }

      // ---- online softmax (q local per lane) + pack P into A-frags ----
      short8 pa[2][2];
#pragma unroll
      for (int mt = 0; mt < 2; ++mt) {
        float vmax = -1e30f;
#pragma unroll
        for (int nt = 0; nt < 4; ++nt)
#pragma unroll
          for (int j = 0; j < 4; ++j) vmax = fmaxf(vmax, s[mt][nt][j]);
        vmax = fmaxf(vmax, __shfl_xor(vmax, 16));
        vmax = fmaxf(vmax, __shfl_xor(vmax, 32));
        const float mn = fmaxf(mx[mt], vmax);
        const float al = __expf(mx[mt] - mn);
        mx[mt] = mn;
        float rs = 0.f;
#pragma unroll
        for (int nt = 0; nt < 4; ++nt)
#pragma unroll
          for (int j = 0; j < 4; ++j) {
            const float p = __expf(s[mt][nt][j] - mn);
            s[mt][nt][j] = p;
            rs += p;
          }
        rs += __shfl_xor(rs, 16);
        rs += __shfl_xor(rs, 32);
        ls[mt] = ls[mt] * al + rs;
        // rescale O (o rows live in g*4+j domain -> broadcast al from cw domain)
#pragma unroll
        for (int j = 0; j < 4; ++j) {
          const float aj = __shfl(al, (lane & 48) | (g * 4 + j));
#pragma unroll
          for (int nd = 0; nd < 4; ++nd) o[mt][nd][j] *= aj;
        }
        union { unsigned u[4]; short8 s8; } pc;
#pragma unroll
        for (int ks2 = 0; ks2 < 2; ++ks2) {
          pc.u[0] = cvtpk(s[mt][2 * ks2][0], s[mt][2 * ks2][1]);
          pc.u[1] = cvtpk(s[mt][2 * ks2][2], s[mt][2 * ks2][3]);
          pc.u[2] = cvtpk(s[mt][2 * ks2 + 1][0], s[mt][2 * ks2 + 1][1]);
          pc.u[3] = cvtpk(s[mt][2 * ks2 + 1][2], s[mt][2 * ks2 + 1][3]);
          pa[mt][ks2] = pc.s8;
        }
      }

      // ---- O += P V  (B-frags from permuted Vs) ----
#pragma unroll
      for (int ks2 = 0; ks2 < 2; ++ks2)
#pragma unroll
        for (int nd = 0; nd < 4; ++nd) {
          const int r = nd * 16 + cw;
          short8 vf = *reinterpret_cast<const short8*>(
              Vs + r * 128 + ((ks2 * 64 + g * 16) ^ xorm));
          o[0][nd] = __builtin_amdgcn_mfma_f32_16x16x32_bf16(pa[0][ks2], vf, o[0][nd], 0, 0, 0);
          o[1][nd] = __builtin_amdgcn_mfma_f32_16x16x32_bf16(pa[1][ks2], vf, o[1][nd], 0, 0, 0);
        }
    }

    // ---- epilogue: y = O / l ----
#pragma unroll
    for (int mt = 0; mt < 2; ++mt)
#pragma unroll
      for (int j = 0; j < 4; ++j) {
        const float lj = __shfl(ls[mt], (lane & 48) | (g * 4 + j));
        const float inv = 1.f / lj;
        const int q = qw + mt * 16 + g * 4 + j;
#pragma unroll
        for (int nd = 0; nd < 4; ++nd)
          y[(size_t)(b * TT + q) * CC + h * 64 + nd * 16 + cw] = bf16b(o[mt][nd][j] * inv);
      }
  }
}

// ---------------------------------------------------------------------------
extern "C" void kernel_launch(void* const* d_in, const int* in_sizes, int n_in,
                              void* d_out, int out_size, void* d_ws, size_t ws_size,
                              hipStream_t stream) {
  const float* x      = (const float*)d_in[0];
  const int*   amask  = (const int*)d_in[1];
  const float* W_attn = (const float*)d_in[2];
  const float* W_proj = (const float*)d_in[3];

  char* ws = (char*)d_ws;
  short* xb  = (short*)(ws);                    // [8192][1024] bf16   16.8 MB
  short* Wta = (short*)(ws + 16777216);         // [3072][1024] bf16    6.3 MB
  short* Wtp = (short*)(ws + 23068672);         // [1024][1024] bf16    2.1 MB
  short* qkv = (short*)(ws + 25165824);         // [8192][3072] bf16   50.3 MB
  short* y   = (short*)(ws + 75497472);         // [8192][1024] bf16   16.8 MB
  short* vT  = (short*)(ws + 92274688);         // [64bh][64d][2048t]  16.8 MB

  cvt_x<<<MM * CC / (256 * 8), 256, 0, stream>>>(x, xb, MM * CC);
  {
    dim3 g(C3 / 32, CC / 32);
    cvt_t<<<g, 256, 0, stream>>>(W_attn, Wta, CC, C3);
  }
  {
    dim3 g(CC / 32, CC / 32);
    cvt_t<<<g, 256, 0, stream>>>(W_proj, Wtp, CC, CC);
  }
  {
    dim3 g(C3 / 128, MM / 128);
    gemm_bt<1><<<g, 256, 0, stream>>>(xb, Wta, qkv, MM, C3, CC);
  }
  {
    dim3 g(TT / 64, 64);
    vtrans<<<g, 256, 0, stream>>>(qkv, vT);
  }
  {
    dim3 g(8, 64);
    attn_mfma<<<g, 256, 0, stream>>>(qkv, vT, amask, y);
  }
  {
    dim3 g(CC / 128, MM / 128);
    gemm_bt<0><<<g, 256, 0, stream>>>(y, Wtp, (void*)d_out, MM, CC, CC);
  }
}